// Round 1
// baseline (88.612 us; speedup 1.0000x reference)
//
#include <hip/hip_runtime.h>
#include <hip/hip_bf16.h>

#define NN 2048
#define AGENT 5
#define STATE 128
#define COMA 64
#define UNITS 32
#define LOG2F_C 0.6931471805599453f

typedef __attribute__((ext_vector_type(8))) _Float16 half8;
typedef __attribute__((ext_vector_type(4))) float f32x4;

// Kernel A: fused Linear + leaky_relu + mean over agents.
// tid space: [0, 2*2048*32). First half computes L (from state/W1), second M (from action/W2).
__global__ __launch_bounds__(256) void embed_kernel(
    const float* __restrict__ state, const float* __restrict__ action,
    const float* __restrict__ W1, const float* __restrict__ b1,
    const float* __restrict__ W2, const float* __restrict__ b2,
    _Float16* __restrict__ Lh, _Float16* __restrict__ Mh) {
  int tid = blockIdx.x * 256 + threadIdx.x;
  int which = tid >> 16;        // block-uniform: 0 -> L, 1 -> M
  int t = tid & 65535;
  int i = t >> 5;
  int k = t & 31;
  if (which == 0) {
    float acc = 0.f;
    float bb = b1[k];
    const float* s = state + i * (AGENT * STATE);
    for (int a = 0; a < AGENT; ++a, s += STATE) {
      float d = bb;
      #pragma unroll
      for (int c = 0; c < STATE; ++c) d = fmaf(s[c], W1[c * UNITS + k], d);
      acc += (d > 0.f) ? d : 0.01f * d;
    }
    Lh[i * UNITS + k] = (_Float16)(acc * 0.2f);
  } else {
    float acc = 0.f;
    float bb = b2[k];
    const float* s = action + i * (AGENT * COMA);
    for (int a = 0; a < AGENT; ++a, s += COMA) {
      float d = bb;
      #pragma unroll
      for (int c = 0; c < COMA; ++c) d = fmaf(s[c], W2[c * UNITS + k], d);
      acc += (d > 0.f) ? d : 0.01f * d;
    }
    Mh[i * UNITS + k] = (_Float16)(acc * 0.2f);
  }
}

// Kernel B: u[i][j] = sum_k M[i][k]*L[j][k] via mfma_f32_16x16x32_f16 (single MFMA per
// 16x16 tile since K=32). Epilogue: e_neg = softplus(u) - log2, accumulate per row,
// capture diagonal, shfl-reduce over the 16 columns, atomicAdd into S.
// Grid: (8 col-blocks of 256, 32 row-blocks of 64). 4 waves/block, 16 rows/wave.
__global__ __launch_bounds__(256) void pair_kernel(
    const _Float16* __restrict__ Lh, const _Float16* __restrict__ Mh,
    float* __restrict__ S, float* __restrict__ Ud) {
  int w = threadIdx.x >> 6;     // wave 0..3
  int l = threadIdx.x & 63;
  int ln15 = l & 15;
  int quad = l >> 4;
  int i0 = blockIdx.y * 64 + w * 16;
  int col0 = blockIdx.x * 256;

  // A fragment: A[m = lane&15][k = quad*8 + j], rows of M. One coalesced 16B load.
  half8 afrag = *(const half8*)(Mh + (i0 + ln15) * UNITS + quad * 8);

  f32x4 accs = {0.f, 0.f, 0.f, 0.f};   // per-reg (per-row) e_neg partial sums

  for (int tile = 0; tile < 16; ++tile) {
    int j0 = col0 + tile * 16;
    // B fragment: B^T rows of L, same load pattern as A.
    half8 bfrag = *(const half8*)(Lh + (j0 + ln15) * UNITS + quad * 8);
    f32x4 c = {0.f, 0.f, 0.f, 0.f};
    c = __builtin_amdgcn_mfma_f32_16x16x32_f16(afrag, bfrag, c, 0, 0, 0);
    int gcol = j0 + ln15;        // C/D layout: col = lane&15
    #pragma unroll
    for (int r = 0; r < 4; ++r) {
      float u = c[r];
      int grow = i0 + quad * 4 + r;   // row = (lane>>4)*4 + reg
      float sp0 = __logf(1.f + __expf(-fabsf(u)));   // softplus(-|u|)
      float en = sp0 + fmaxf(u, 0.f) - LOG2F_C;      // softplus(u) - log2
      accs[r] += en;
      if (grow == gcol) Ud[grow] = u;                // unique writer per i
    }
  }

  // Reduce across the 16 column-lanes (xor over bits 0..3 stays within quad group).
  #pragma unroll
  for (int d = 1; d < 16; d <<= 1) {
    #pragma unroll
    for (int r = 0; r < 4; ++r) accs[r] += __shfl_xor(accs[r], d, 64);
  }
  if (ln15 == 0) {
    #pragma unroll
    for (int r = 0; r < 4; ++r) atomicAdd(&S[i0 + quad * 4 + r], accs[r]);
  }
}

// Kernel C: finalize loss / MI per row.
__global__ __launch_bounds__(256) void final_kernel(
    const float* __restrict__ S, const float* __restrict__ Ud,
    float* __restrict__ out) {
  int i = blockIdx.x * 256 + threadIdx.x;
  if (i < NN) {
    float u = Ud[i];
    float sp0 = __logf(1.f + __expf(-fabsf(u)));
    float spu = sp0 + fmaxf(u, 0.f);      // softplus(u)
    float en_ii = spu - LOG2F_C;          // E_neg at the diagonal (to subtract)
    float sp_neg = spu - u;               // softplus(-u)
    float mi = LOG2F_C - sp_neg;          // E_pos diagonal
    out[i] = (S[i] - en_ii) * (1.f / (NN - 1)) - mi;   // loss
    out[NN + i] = mi;                                   // MI
  }
}

extern "C" void kernel_launch(void* const* d_in, const int* in_sizes, int n_in,
                              void* d_out, int out_size, void* d_ws, size_t ws_size,
                              hipStream_t stream) {
  const float* state  = (const float*)d_in[0];
  const float* action = (const float*)d_in[1];
  const float* W1     = (const float*)d_in[2];
  const float* b1     = (const float*)d_in[3];
  const float* W2     = (const float*)d_in[4];
  const float* b2     = (const float*)d_in[5];

  char* w = (char*)d_ws;
  _Float16* Lh = (_Float16*)w;                       // 2048*32*2 = 128 KiB
  _Float16* Mh = (_Float16*)(w + 131072);            // 128 KiB
  float* S     = (float*)(w + 262144);               // 8 KiB
  float* Ud    = (float*)(w + 262144 + 8192);        // 8 KiB
  float* out   = (float*)d_out;

  hipMemsetAsync(S, 0, NN * sizeof(float), stream);

  // 2 * 2048 * 32 threads = 512 blocks of 256
  embed_kernel<<<512, 256, 0, stream>>>(state, action, W1, b1, W2, b2, Lh, Mh);

  pair_kernel<<<dim3(8, 32), 256, 0, stream>>>(Lh, Mh, S, Ud);

  final_kernel<<<8, 256, 0, stream>>>(S, Ud, out);
}

// Round 2
// 83.646 us; speedup vs baseline: 1.0594x; 1.0594x over previous
//
#include <hip/hip_runtime.h>
#include <hip/hip_bf16.h>

#define NN 2048
#define AGENT 5
#define STATE 128
#define COMA 64
#define UNITS 32
#define LOG2F_C 0.6931471805599453f

typedef __attribute__((ext_vector_type(8))) _Float16 half8;
typedef __attribute__((ext_vector_type(4))) float f32x4;

// Kernel A: fused Linear + leaky_relu + mean over agents. Also zeros S.
// tid space: [0, 2*2048*32). First half computes L (from state/W1), second M (from action/W2).
// Loop structure: c-outer (float4 state loads), agent-inner, W hoisted across agents.
__global__ __launch_bounds__(256) void embed_kernel(
    const float* __restrict__ state, const float* __restrict__ action,
    const float* __restrict__ W1, const float* __restrict__ b1,
    const float* __restrict__ W2, const float* __restrict__ b2,
    _Float16* __restrict__ Lh, _Float16* __restrict__ Mh,
    float* __restrict__ S) {
  int tid = blockIdx.x * 256 + threadIdx.x;
  if (tid < NN) S[tid] = 0.f;          // replaces the memset dispatch
  int which = tid >> 16;               // wave-uniform: 0 -> L, 1 -> M
  int t = tid & 65535;
  int i = t >> 5;
  int k = t & 31;
  if (which == 0) {
    float bb = b1[k];
    float acc[AGENT];
    #pragma unroll
    for (int a = 0; a < AGENT; ++a) acc[a] = bb;
    const float4* sp = (const float4*)(state + i * (AGENT * STATE));
    #pragma unroll 4
    for (int c4 = 0; c4 < STATE / 4; ++c4) {
      float4 sv[AGENT];
      #pragma unroll
      for (int a = 0; a < AGENT; ++a) sv[a] = sp[a * (STATE / 4) + c4];
      #pragma unroll
      for (int j = 0; j < 4; ++j) {
        float wv = W1[(c4 * 4 + j) * UNITS + k];   // coalesced 128B across lanes, L1-hot
        acc[0] = fmaf(sv[0].x * 0 + (&sv[0].x)[j], wv, acc[0]);
        acc[1] = fmaf((&sv[1].x)[j], wv, acc[1]);
        acc[2] = fmaf((&sv[2].x)[j], wv, acc[2]);
        acc[3] = fmaf((&sv[3].x)[j], wv, acc[3]);
        acc[4] = fmaf((&sv[4].x)[j], wv, acc[4]);
      }
    }
    float r = 0.f;
    #pragma unroll
    for (int a = 0; a < AGENT; ++a) r += (acc[a] > 0.f) ? acc[a] : 0.01f * acc[a];
    Lh[i * UNITS + k] = (_Float16)(r * 0.2f);
  } else {
    float bb = b2[k];
    float acc[AGENT];
    #pragma unroll
    for (int a = 0; a < AGENT; ++a) acc[a] = bb;
    const float4* sp = (const float4*)(action + i * (AGENT * COMA));
    #pragma unroll 4
    for (int c4 = 0; c4 < COMA / 4; ++c4) {
      float4 sv[AGENT];
      #pragma unroll
      for (int a = 0; a < AGENT; ++a) sv[a] = sp[a * (COMA / 4) + c4];
      #pragma unroll
      for (int j = 0; j < 4; ++j) {
        float wv = W2[(c4 * 4 + j) * UNITS + k];
        #pragma unroll
        for (int a = 0; a < AGENT; ++a) acc[a] = fmaf((&sv[a].x)[j], wv, acc[a]);
      }
    }
    float r = 0.f;
    #pragma unroll
    for (int a = 0; a < AGENT; ++a) r += (acc[a] > 0.f) ? acc[a] : 0.01f * acc[a];
    Mh[i * UNITS + k] = (_Float16)(r * 0.2f);
  }
}

// Kernel B: u[i][j] = sum_k M[i][k]*L[j][k] via mfma_f32_16x16x32_f16.
// Grid (32,32) = 1024 blocks (4 blocks/CU, 4 waves/SIMD). Each wave: 16 rows x 64 cols
// = 4 tiles, fully unrolled so the 4 b-fragment loads are all in flight.
__global__ __launch_bounds__(256) void pair_kernel(
    const _Float16* __restrict__ Lh, const _Float16* __restrict__ Mh,
    float* __restrict__ S, float* __restrict__ Ud) {
  int w = threadIdx.x >> 6;     // wave 0..3
  int l = threadIdx.x & 63;
  int ln15 = l & 15;
  int quad = l >> 4;
  int i0 = blockIdx.y * 64 + w * 16;
  int col0 = blockIdx.x * 64;

  // A fragment: A[m = lane&15][k = quad*8 + j], rows of M. One coalesced 16B load.
  half8 afrag = *(const half8*)(Mh + (i0 + ln15) * UNITS + quad * 8);

  f32x4 accs = {0.f, 0.f, 0.f, 0.f};   // per-reg (per-row) e_neg partial sums

  #pragma unroll
  for (int tile = 0; tile < 4; ++tile) {
    int j0 = col0 + tile * 16;
    half8 bfrag = *(const half8*)(Lh + (j0 + ln15) * UNITS + quad * 8);
    f32x4 c = {0.f, 0.f, 0.f, 0.f};
    c = __builtin_amdgcn_mfma_f32_16x16x32_f16(afrag, bfrag, c, 0, 0, 0);
    int gcol = j0 + ln15;        // C/D layout: col = lane&15
    #pragma unroll
    for (int r = 0; r < 4; ++r) {
      float u = c[r];
      int grow = i0 + quad * 4 + r;   // row = (lane>>4)*4 + reg
      float sp0 = __logf(1.f + __expf(-fabsf(u)));   // softplus(-|u|)
      float en = sp0 + fmaxf(u, 0.f) - LOG2F_C;      // softplus(u) - log2
      accs[r] += en;
      if (grow == gcol) Ud[grow] = u;                // unique writer per i
    }
  }

  // Reduce across the 16 column-lanes.
  #pragma unroll
  for (int d = 1; d < 16; d <<= 1) {
    #pragma unroll
    for (int r = 0; r < 4; ++r) accs[r] += __shfl_xor(accs[r], d, 64);
  }
  if (ln15 == 0) {
    #pragma unroll
    for (int r = 0; r < 4; ++r) atomicAdd(&S[i0 + quad * 4 + r], accs[r]);
  }
}

// Kernel C: finalize loss / MI per row.
__global__ __launch_bounds__(256) void final_kernel(
    const float* __restrict__ S, const float* __restrict__ Ud,
    float* __restrict__ out) {
  int i = blockIdx.x * 256 + threadIdx.x;
  if (i < NN) {
    float u = Ud[i];
    float sp0 = __logf(1.f + __expf(-fabsf(u)));
    float spu = sp0 + fmaxf(u, 0.f);      // softplus(u)
    float en_ii = spu - LOG2F_C;          // E_neg at the diagonal (to subtract)
    float sp_neg = spu - u;               // softplus(-u)
    float mi = LOG2F_C - sp_neg;          // E_pos diagonal
    out[i] = (S[i] - en_ii) * (1.f / (NN - 1)) - mi;   // loss
    out[NN + i] = mi;                                   // MI
  }
}

extern "C" void kernel_launch(void* const* d_in, const int* in_sizes, int n_in,
                              void* d_out, int out_size, void* d_ws, size_t ws_size,
                              hipStream_t stream) {
  const float* state  = (const float*)d_in[0];
  const float* action = (const float*)d_in[1];
  const float* W1     = (const float*)d_in[2];
  const float* b1     = (const float*)d_in[3];
  const float* W2     = (const float*)d_in[4];
  const float* b2     = (const float*)d_in[5];

  char* w = (char*)d_ws;
  _Float16* Lh = (_Float16*)w;                       // 2048*32*2 = 128 KiB
  _Float16* Mh = (_Float16*)(w + 131072);            // 128 KiB
  float* S     = (float*)(w + 262144);               // 8 KiB
  float* Ud    = (float*)(w + 262144 + 8192);        // 8 KiB
  float* out   = (float*)d_out;

  // 2 * 2048 * 32 threads = 512 blocks of 256 (also zeros S)
  embed_kernel<<<512, 256, 0, stream>>>(state, action, W1, b1, W2, b2, Lh, Mh, S);

  pair_kernel<<<dim3(32, 32), 256, 0, stream>>>(Lh, Mh, S, Ud);

  final_kernel<<<8, 256, 0, stream>>>(S, Ud, out);
}